// Round 2
// baseline (78.669 us; speedup 1.0000x reference)
//
#include <hip/hip_runtime.h>
#include <math.h>

#define SO3_EPS 1e-8f

// --- Kernel 1: per-head rotation matrix precompute (16 heads, trivial) ---
// ws layout per head h (12 floats): Rs[0][0..2], Rs[1][0..2], Rs[2][0..2], bias[0..2]
// where Rs[c][n] = R[c][n] * scales[n]  and  bias[n] = sum_c shift[c] * Rs[c][n].
// out[b,h,n,p] = sum_c pcd[b,h,c,p] * Rs[c][n] + bias[n]
__global__ void vt_precompute_R(const float* __restrict__ log_R,
                                const float* __restrict__ shift,
                                const float* __restrict__ scales,
                                float* __restrict__ ws, int H) {
    int h = blockIdx.x * blockDim.x + threadIdx.x;
    if (h >= H) return;

    float x = log_R[h * 3 + 0];
    float y = log_R[h * 3 + 1];
    float z = log_R[h * 3 + 2];

    float theta2 = x * x + y * y + z * z;
    float t2c = fmaxf(theta2, SO3_EPS);
    float theta = sqrtf(t2c);
    float fac1 = sinf(theta) / theta;
    float fac2 = (1.0f - cosf(theta)) / t2c;

    // Rodrigues: R = I + fac1*K + fac2*K^2, K = [[0,-z,y],[z,0,-x],[-y,x,0]]
    float R[3][3];
    R[0][0] = 1.0f - fac2 * (y * y + z * z);
    R[0][1] = -fac1 * z + fac2 * x * y;
    R[0][2] =  fac1 * y + fac2 * x * z;
    R[1][0] =  fac1 * z + fac2 * x * y;
    R[1][1] = 1.0f - fac2 * (x * x + z * z);
    R[1][2] = -fac1 * x + fac2 * y * z;
    R[2][0] = -fac1 * y + fac2 * x * z;
    R[2][1] =  fac1 * x + fac2 * y * z;
    R[2][2] = 1.0f - fac2 * (x * x + y * y);

    float sc[3] = { scales[h * 3 + 0], scales[h * 3 + 1], scales[h * 3 + 2] };
    float sh[3] = { shift[h * 3 + 0], shift[h * 3 + 1], shift[h * 3 + 2] };

    float Rs[3][3];
    #pragma unroll
    for (int c = 0; c < 3; ++c)
        #pragma unroll
        for (int n = 0; n < 3; ++n)
            Rs[c][n] = R[c][n] * sc[n];

    float bias[3];
    #pragma unroll
    for (int n = 0; n < 3; ++n)
        bias[n] = sh[0] * Rs[0][n] + sh[1] * Rs[1][n] + sh[2] * Rs[2][n];

    float* w = ws + h * 12;
    #pragma unroll
    for (int c = 0; c < 3; ++c)
        #pragma unroll
        for (int n = 0; n < 3; ++n)
            w[c * 3 + n] = Rs[c][n];
    #pragma unroll
    for (int n = 0; n < 3; ++n)
        w[9 + n] = bias[n];
}

// --- Kernel 2: streaming transform, float4-vectorized ---
// pcd layout (B,H,3,P) fp32. Each thread handles one float4 slot of one (b,h).
// idx enumerates (b,h,p4): p4 = idx % P4, bh = idx / P4.
__global__ void __launch_bounds__(256)
vt_transform(const float4* __restrict__ pcd,
             const float* __restrict__ ws,
             float4* __restrict__ out,
             int P4, int H) {
    int idx = blockIdx.x * blockDim.x + threadIdx.x;
    int p4 = idx & (P4 - 1);        // P4 is a power of two (32768)
    int bh = idx / P4;              // uniform within a block (P4 % 256 == 0)
    int h = bh & (H - 1);           // H = 16, power of two

    const float* w = ws + h * 12;   // uniform per block -> L1/scalar-cached
    float m00 = w[0], m01 = w[1], m02 = w[2];
    float m10 = w[3], m11 = w[4], m12 = w[5];
    float m20 = w[6], m21 = w[7], m22 = w[8];
    float b0 = w[9], b1 = w[10], b2 = w[11];

    long base = (long)bh * 3 * P4 + p4;   // float4 element index
    float4 a = pcd[base];
    float4 b = pcd[base + P4];
    float4 c = pcd[base + 2 * P4];

    float4 o0, o1, o2;
    o0.x = fmaf(a.x, m00, fmaf(b.x, m10, fmaf(c.x, m20, b0)));
    o0.y = fmaf(a.y, m00, fmaf(b.y, m10, fmaf(c.y, m20, b0)));
    o0.z = fmaf(a.z, m00, fmaf(b.z, m10, fmaf(c.z, m20, b0)));
    o0.w = fmaf(a.w, m00, fmaf(b.w, m10, fmaf(c.w, m20, b0)));

    o1.x = fmaf(a.x, m01, fmaf(b.x, m11, fmaf(c.x, m21, b1)));
    o1.y = fmaf(a.y, m01, fmaf(b.y, m11, fmaf(c.y, m21, b1)));
    o1.z = fmaf(a.z, m01, fmaf(b.z, m11, fmaf(c.z, m21, b1)));
    o1.w = fmaf(a.w, m01, fmaf(b.w, m11, fmaf(c.w, m21, b1)));

    o2.x = fmaf(a.x, m02, fmaf(b.x, m12, fmaf(c.x, m22, b2)));
    o2.y = fmaf(a.y, m02, fmaf(b.y, m12, fmaf(c.y, m22, b2)));
    o2.z = fmaf(a.z, m02, fmaf(b.z, m12, fmaf(c.z, m22, b2)));
    o2.w = fmaf(a.w, m02, fmaf(b.w, m12, fmaf(c.w, m22, b2)));

    out[base]          = o0;
    out[base + P4]     = o1;
    out[base + 2 * P4] = o2;
}

extern "C" void kernel_launch(void* const* d_in, const int* in_sizes, int n_in,
                              void* d_out, int out_size, void* d_ws, size_t ws_size,
                              hipStream_t stream) {
    const float* pcd    = (const float*)d_in[0];  // (B,H,3,P) fp32
    const float* log_R  = (const float*)d_in[1];  // (H,3)
    const float* shift  = (const float*)d_in[2];  // (H,3)
    const float* scales = (const float*)d_in[3];  // (H,3)
    float* out = (float*)d_out;
    float* ws  = (float*)d_ws;

    const int H = in_sizes[1] / 3;                     // 16
    const long total = (long)in_sizes[0];              // B*H*3*P
    const int BH = (int)(total / (3L * 131072L));      // B*H
    const int P = (int)(total / (3L * BH));            // 131072
    const int P4 = P / 4;

    vt_precompute_R<<<1, 64, 0, stream>>>(log_R, shift, scales, ws, H);

    const int nthreads = BH * P4;                      // 4,194,304
    const int block = 256;
    const int grid = (nthreads + block - 1) / block;   // 16384
    vt_transform<<<grid, block, 0, stream>>>(
        (const float4*)pcd, ws, (float4*)out, P4, H);
}

// Round 3
// 67.972 us; speedup vs baseline: 1.1574x; 1.1574x over previous
//
#include <hip/hip_runtime.h>
#include <math.h>

#define SO3_EPS 1e-8f

typedef float f4 __attribute__((ext_vector_type(4)));

// Fused kernel: per-block Rodrigues (wave-uniform scalar work, hidden under
// memory latency) + streaming transform.
//
// pcd layout (B,H,3,P) fp32. Grid: x = P4 / (256*2), y = B*H.
// Each thread handles 2 float4 slots of each of the 3 channels (96 B in, 96 B out).
__global__ void __launch_bounds__(256)
vt_fused(const f4* __restrict__ pcd,
         const float* __restrict__ log_R,
         const float* __restrict__ shift,
         const float* __restrict__ scales,
         f4* __restrict__ out,
         int P4, int Hmask) {
    const int bh = blockIdx.y;          // wave-uniform
    const int h  = bh & Hmask;          // H is a power of two (16)

    // --- Rodrigues: R = I + fac1*K + fac2*K^2 (uniform per block) ---
    const float x = log_R[h * 3 + 0];
    const float y = log_R[h * 3 + 1];
    const float z = log_R[h * 3 + 2];

    const float theta2 = x * x + y * y + z * z;
    const float t2c    = fmaxf(theta2, SO3_EPS);
    const float theta  = sqrtf(t2c);
    const float fac1   = sinf(theta) / theta;
    const float fac2   = (1.0f - cosf(theta)) / t2c;

    const float sc0 = scales[h * 3 + 0], sc1 = scales[h * 3 + 1], sc2 = scales[h * 3 + 2];
    const float sh0 = shift[h * 3 + 0],  sh1 = shift[h * 3 + 1],  sh2 = shift[h * 3 + 2];

    // Rs[c][n] = R[c][n] * scales[n]
    const float m00 = (1.0f - fac2 * (y * y + z * z)) * sc0;
    const float m01 = (-fac1 * z + fac2 * x * y) * sc1;
    const float m02 = ( fac1 * y + fac2 * x * z) * sc2;
    const float m10 = ( fac1 * z + fac2 * x * y) * sc0;
    const float m11 = (1.0f - fac2 * (x * x + z * z)) * sc1;
    const float m12 = (-fac1 * x + fac2 * y * z) * sc2;
    const float m20 = (-fac1 * y + fac2 * x * z) * sc0;
    const float m21 = ( fac1 * x + fac2 * y * z) * sc1;
    const float m22 = (1.0f - fac2 * (x * x + y * y)) * sc2;

    // bias[n] = sum_c shift[c] * Rs[c][n]
    const float b0 = sh0 * m00 + sh1 * m10 + sh2 * m20;
    const float b1 = sh0 * m01 + sh1 * m11 + sh2 * m21;
    const float b2 = sh0 * m02 + sh1 * m12 + sh2 * m22;

    // --- streaming transform ---
    const long base = (long)bh * 3 * P4;       // float4 element index
    const int  p4   = blockIdx.x * 512 + threadIdx.x;   // 2 chunks, 256 apart

    const f4* __restrict__ src = pcd + base;
    f4* __restrict__       dst = out + base;

    const f4 a0 = __builtin_nontemporal_load(&src[p4]);
    const f4 a1 = __builtin_nontemporal_load(&src[p4 + 256]);
    const f4 bb0 = __builtin_nontemporal_load(&src[p4 + P4]);
    const f4 bb1 = __builtin_nontemporal_load(&src[p4 + P4 + 256]);
    const f4 c0 = __builtin_nontemporal_load(&src[p4 + 2 * P4]);
    const f4 c1 = __builtin_nontemporal_load(&src[p4 + 2 * P4 + 256]);

    const f4 o00 = a0 * m00 + bb0 * m10 + c0 * m20 + b0;
    const f4 o01 = a1 * m00 + bb1 * m10 + c1 * m20 + b0;
    const f4 o10 = a0 * m01 + bb0 * m11 + c0 * m21 + b1;
    const f4 o11 = a1 * m01 + bb1 * m11 + c1 * m21 + b1;
    const f4 o20 = a0 * m02 + bb0 * m12 + c0 * m22 + b2;
    const f4 o21 = a1 * m02 + bb1 * m12 + c1 * m22 + b2;

    __builtin_nontemporal_store(o00, &dst[p4]);
    __builtin_nontemporal_store(o01, &dst[p4 + 256]);
    __builtin_nontemporal_store(o10, &dst[p4 + P4]);
    __builtin_nontemporal_store(o11, &dst[p4 + P4 + 256]);
    __builtin_nontemporal_store(o20, &dst[p4 + 2 * P4]);
    __builtin_nontemporal_store(o21, &dst[p4 + 2 * P4 + 256]);
}

extern "C" void kernel_launch(void* const* d_in, const int* in_sizes, int n_in,
                              void* d_out, int out_size, void* d_ws, size_t ws_size,
                              hipStream_t stream) {
    const f4*    pcd    = (const f4*)d_in[0];     // (B,H,3,P) fp32
    const float* log_R  = (const float*)d_in[1];  // (H,3)
    const float* shift  = (const float*)d_in[2];  // (H,3)
    const float* scales = (const float*)d_in[3];  // (H,3)
    f4* out = (f4*)d_out;

    const int H = in_sizes[1] / 3;                     // 16
    const long total = (long)in_sizes[0];              // B*H*3*P
    const int P = 131072;                              // fixed by problem
    const int BH = (int)(total / (3L * P));            // 128
    const int P4 = P / 4;                              // 32768

    dim3 grid(P4 / 512, BH);                           // (64, 128)
    vt_fused<<<grid, 256, 0, stream>>>(pcd, log_R, shift, scales, out, P4, H - 1);
}